// Round 1
// baseline (847.089 us; speedup 1.0000x reference)
//
#include <hip/hip_runtime.h>

#define THREADS 256
#define SCAN_ITEMS 8   // 2048 elements per scan block

__global__ void zero_int(int* __restrict__ p, int n) {
    int i = blockIdx.x * blockDim.x + threadIdx.x;
    if (i < n) p[i] = 0;
}

__global__ void degree_kernel(const int* __restrict__ dst, int* __restrict__ cnt, int E) {
    int e = blockIdx.x * blockDim.x + threadIdx.x;
    if (e < E) atomicAdd(&cnt[dst[e]], 1);
}

// Per-block exclusive scan (2048 elems/block) + block sums
__global__ void scan1_kernel(const int* __restrict__ cnt, int* __restrict__ off,
                             int* __restrict__ bsums, int n) {
    __shared__ int sdata[THREADS];
    int base = blockIdx.x * (THREADS * SCAN_ITEMS) + threadIdx.x * SCAN_ITEMS;
    int vals[SCAN_ITEMS];
    int tsum = 0;
#pragma unroll
    for (int k = 0; k < SCAN_ITEMS; k++) {
        int idx = base + k;
        int v = (idx < n) ? cnt[idx] : 0;
        vals[k] = tsum;   // thread-local exclusive prefix
        tsum += v;
    }
    sdata[threadIdx.x] = tsum;
    __syncthreads();
    // Hillis-Steele inclusive scan of per-thread sums
    for (int s = 1; s < THREADS; s <<= 1) {
        int y = (threadIdx.x >= (unsigned)s) ? sdata[threadIdx.x - s] : 0;
        __syncthreads();
        sdata[threadIdx.x] += y;
        __syncthreads();
    }
    int texcl = sdata[threadIdx.x] - tsum;
#pragma unroll
    for (int k = 0; k < SCAN_ITEMS; k++) {
        int idx = base + k;
        if (idx < n) off[idx] = texcl + vals[k];
    }
    if (threadIdx.x == THREADS - 1) bsums[blockIdx.x] = sdata[THREADS - 1];
}

// Scan block sums (nb ~ 49, trivial sequential) + write off[N] = total
__global__ void scan2_kernel(const int* __restrict__ bsums, int* __restrict__ bbase,
                             int nb, int* __restrict__ offN) {
    if (threadIdx.x == 0 && blockIdx.x == 0) {
        int run = 0;
        for (int i = 0; i < nb; i++) { bbase[i] = run; run += bsums[i]; }
        *offN = run;
    }
}

__global__ void scan3_kernel(int* __restrict__ off, int* __restrict__ pos,
                             const int* __restrict__ bbase, int n) {
    int i = blockIdx.x * blockDim.x + threadIdx.x;
    if (i < n) {
        int v = off[i] + bbase[i >> 11];   // 2048 per scan1 block
        off[i] = v;
        pos[i] = v;
    }
}

__global__ void bucket_kernel(const int* __restrict__ src, const int* __restrict__ dst,
                              int* __restrict__ pos, int* __restrict__ srcs, int E) {
    int e = blockIdx.x * blockDim.x + threadIdx.x;
    if (e < E) {
        int d = dst[e];
        int p = atomicAdd(&pos[d], 1);
        srcs[p] = src[e];
    }
}

// One wave per destination node; lane owns 2 features (float2).
__global__ void agg_kernel(const float* __restrict__ h, const int* __restrict__ off,
                           const int* __restrict__ srcs, const int* __restrict__ cnt,
                           float* __restrict__ agg, int n) {
    int gid = blockIdx.x * blockDim.x + threadIdx.x;
    int node = gid >> 6;
    int lane = threadIdx.x & 63;
    if (node >= n) return;
    int p0 = off[node], p1 = off[node + 1];
    float ax = 0.f, ay = 0.f;
    for (int p = p0; p < p1; p++) {
        int s = srcs[p];
        float2 v = *(const float2*)(h + (size_t)s * 128 + lane * 2);
        ax += v.x; ay += v.y;
    }
    int c = cnt[node];
    float inv = 1.0f / (float)(c > 1 ? c : 1);
    *(float2*)(agg + (size_t)node * 128 + lane * 2) = make_float2(ax * inv, ay * inv);
}

// Fused: out = relu(agg@Wn + h@Wr + b); if FINAL, logits = relu_row . Wh + bh
// 32 nodes per block (LDS-staged), thread microtile = 2 features x 8 nodes.
template <bool FINAL>
__global__ __launch_bounds__(256) void update_kernel(
    const float* __restrict__ agg, const float* __restrict__ h,
    const float* __restrict__ Wn, const float* __restrict__ Wr,
    const float* __restrict__ bias,
    float* __restrict__ out,            // [n,128] if !FINAL
    const float* __restrict__ Wh, const float* __restrict__ bh,
    float* __restrict__ logits,         // [n] if FINAL
    int n) {
    __shared__ __align__(16) float sa[32 * 128];
    __shared__ __align__(16) float sh[32 * 128];
    int i0 = blockIdx.x * 32;
    {
        const float4* av = (const float4*)(agg + (size_t)i0 * 128);
        const float4* hv = (const float4*)(h + (size_t)i0 * 128);
        float4* sav = (float4*)sa;
        float4* shv = (float4*)sh;
        int vrows = n - i0; if (vrows > 32) vrows = 32;
        int nv4 = vrows * 32;
#pragma unroll
        for (int r = 0; r < 4; r++) {
            int idx = r * 256 + threadIdx.x;
            if (idx < nv4) { sav[idx] = av[idx]; shv[idx] = hv[idx]; }
        }
    }
    __syncthreads();

    int jj = threadIdx.x & 63;   // feature pair index (wave = one feature sweep)
    int ii = threadIdx.x >> 6;   // node group 0..3
    int j0 = jj * 2;
    float acc0[8], acc1[8];
#pragma unroll
    for (int m = 0; m < 8; m++) { acc0[m] = 0.f; acc1[m] = 0.f; }

    for (int k0 = 0; k0 < 128; k0 += 4) {
        float2 wn[4], wr[4];
#pragma unroll
        for (int k = 0; k < 4; k++) {
            wn[k] = *(const float2*)(Wn + (size_t)(k0 + k) * 128 + j0);
            wr[k] = *(const float2*)(Wr + (size_t)(k0 + k) * 128 + j0);
        }
#pragma unroll
        for (int m = 0; m < 8; m++) {
            int i = ii * 8 + m;
            float4 a4 = *(const float4*)(sa + i * 128 + k0);  // broadcast reads
            float4 h4 = *(const float4*)(sh + i * 128 + k0);
            acc0[m] += a4.x * wn[0].x + a4.y * wn[1].x + a4.z * wn[2].x + a4.w * wn[3].x
                     + h4.x * wr[0].x + h4.y * wr[1].x + h4.z * wr[2].x + h4.w * wr[3].x;
            acc1[m] += a4.x * wn[0].y + a4.y * wn[1].y + a4.z * wn[2].y + a4.w * wn[3].y
                     + h4.x * wr[0].y + h4.y * wr[1].y + h4.z * wr[2].y + h4.w * wr[3].y;
        }
    }

    float2 bb = *(const float2*)(bias + j0);
    if (!FINAL) {
#pragma unroll
        for (int m = 0; m < 8; m++) {
            int gi = i0 + ii * 8 + m;
            if (gi < n) {
                float o0 = acc0[m] + bb.x; o0 = o0 > 0.f ? o0 : 0.f;
                float o1 = acc1[m] + bb.y; o1 = o1 > 0.f ? o1 : 0.f;
                *(float2*)(out + (size_t)gi * 128 + j0) = make_float2(o0, o1);
            }
        }
    } else {
        float2 wh2 = *(const float2*)(Wh + j0);
        float bhv = bh[0];
#pragma unroll
        for (int m = 0; m < 8; m++) {
            int gi = i0 + ii * 8 + m;
            float o0 = acc0[m] + bb.x; o0 = o0 > 0.f ? o0 : 0.f;
            float o1 = acc1[m] + bb.y; o1 = o1 > 0.f ? o1 : 0.f;
            float part = o0 * wh2.x + o1 * wh2.y;
#pragma unroll
            for (int s = 32; s > 0; s >>= 1) part += __shfl_down(part, s);
            if (jj == 0 && gi < n) logits[gi] = part + bhv;
        }
    }
}

extern "C" void kernel_launch(void* const* d_in, const int* in_sizes, int n_in,
                              void* d_out, int out_size, void* d_ws, size_t ws_size,
                              hipStream_t stream) {
    const float* x   = (const float*)d_in[0];
    const int*   ei  = (const int*)d_in[1];
    const float* Wn0 = (const float*)d_in[2];
    const float* Wr0 = (const float*)d_in[3];
    const float* b0  = (const float*)d_in[4];
    const float* Wn1 = (const float*)d_in[5];
    const float* Wr1 = (const float*)d_in[6];
    const float* b1  = (const float*)d_in[7];
    const float* Wh  = (const float*)d_in[8];
    const float* bh  = (const float*)d_in[9];
    float* logits = (float*)d_out;

    int N = in_sizes[0] / 128;
    int E = in_sizes[1] / 2;
    const int* src = ei;       // edge_index[0]
    const int* dst = ei + E;   // edge_index[1]

    char* ws = (char*)d_ws;
    size_t cur = 0;
    auto alloc = [&](size_t bytes) -> void* {
        void* p = ws + cur;
        cur += (bytes + 255) & ~(size_t)255;
        return p;
    };
    int NB = (N + 2047) / 2048;
    int* cnt   = (int*)alloc((size_t)N * 4);
    int* off   = (int*)alloc((size_t)(N + 1) * 4);
    int* pos   = (int*)alloc((size_t)N * 4);
    int* bsums = (int*)alloc((size_t)NB * 4);
    int* bbase = (int*)alloc((size_t)NB * 4);
    int* srcs  = (int*)alloc((size_t)E * 4);
    float* h0  = (float*)alloc((size_t)N * 128 * 4);
    float* ag  = (float*)alloc((size_t)N * 128 * 4);
    (void)ws_size; (void)n_in; (void)out_size;

    int gN = (N + 255) / 256;
    int gE = (E + 255) / 256;

    // Build CSR by destination
    hipLaunchKernelGGL(zero_int,      dim3(gN), dim3(256), 0, stream, cnt, N);
    hipLaunchKernelGGL(degree_kernel, dim3(gE), dim3(256), 0, stream, dst, cnt, E);
    hipLaunchKernelGGL(scan1_kernel,  dim3(NB), dim3(256), 0, stream, cnt, off, bsums, N);
    hipLaunchKernelGGL(scan2_kernel,  dim3(1),  dim3(64),  0, stream, bsums, bbase, NB, off + N);
    hipLaunchKernelGGL(scan3_kernel,  dim3(gN), dim3(256), 0, stream, off, pos, bbase, N);
    hipLaunchKernelGGL(bucket_kernel, dim3(gE), dim3(256), 0, stream, src, dst, pos, srcs, E);

    int gAgg = (N + 3) / 4;    // 4 waves per block, 1 node per wave
    int gUpd = (N + 31) / 32;  // 32 nodes per block

    // Layer 0
    hipLaunchKernelGGL(agg_kernel, dim3(gAgg), dim3(256), 0, stream, x, off, srcs, cnt, ag, N);
    hipLaunchKernelGGL((update_kernel<false>), dim3(gUpd), dim3(256), 0, stream,
                       ag, x, Wn0, Wr0, b0, h0, nullptr, nullptr, nullptr, N);
    // Layer 1 + fused head
    hipLaunchKernelGGL(agg_kernel, dim3(gAgg), dim3(256), 0, stream, h0, off, srcs, cnt, ag, N);
    hipLaunchKernelGGL((update_kernel<true>), dim3(gUpd), dim3(256), 0, stream,
                       ag, h0, Wn1, Wr1, b1, nullptr, Wh, bh, logits, N);
}

// Round 2
// 550.363 us; speedup vs baseline: 1.5391x; 1.5391x over previous
//
#include <hip/hip_runtime.h>

#define THREADS 256
#define SCAN_ITEMS 8   // 2048 elements per scan block

typedef float f32x4 __attribute__((ext_vector_type(4)));
typedef __bf16 bf16x8 __attribute__((ext_vector_type(8)));

__device__ inline unsigned short f32_to_bf16_rne(float f) {
    unsigned int u = __float_as_uint(f);
    unsigned int r = u + 0x7fffu + ((u >> 16) & 1u);
    return (unsigned short)(r >> 16);
}
__device__ inline float bf16_bits_to_f32(unsigned short h) {
    return __uint_as_float(((unsigned int)h) << 16);
}
__device__ inline uint4 pack8(const unsigned short* s) {
    uint4 u;
    u.x = (unsigned int)s[0] | ((unsigned int)s[1] << 16);
    u.y = (unsigned int)s[2] | ((unsigned int)s[3] << 16);
    u.z = (unsigned int)s[4] | ((unsigned int)s[5] << 16);
    u.w = (unsigned int)s[6] | ((unsigned int)s[7] << 16);
    return u;
}

// ---------------- CSR build ----------------
__global__ void zero_int(int* __restrict__ p, int n) {
    int i = blockIdx.x * blockDim.x + threadIdx.x;
    if (i < n) p[i] = 0;
}

__global__ void degree_kernel(const int* __restrict__ dst, int* __restrict__ cnt, int E) {
    int e = blockIdx.x * blockDim.x + threadIdx.x;
    if (e < E) atomicAdd(&cnt[dst[e]], 1);
}

__global__ void scan1_kernel(const int* __restrict__ cnt, int* __restrict__ off,
                             int* __restrict__ bsums, int n) {
    __shared__ int sdata[THREADS];
    int base = blockIdx.x * (THREADS * SCAN_ITEMS) + threadIdx.x * SCAN_ITEMS;
    int vals[SCAN_ITEMS];
    int tsum = 0;
#pragma unroll
    for (int k = 0; k < SCAN_ITEMS; k++) {
        int idx = base + k;
        int v = (idx < n) ? cnt[idx] : 0;
        vals[k] = tsum;
        tsum += v;
    }
    sdata[threadIdx.x] = tsum;
    __syncthreads();
    for (int s = 1; s < THREADS; s <<= 1) {
        int y = (threadIdx.x >= (unsigned)s) ? sdata[threadIdx.x - s] : 0;
        __syncthreads();
        sdata[threadIdx.x] += y;
        __syncthreads();
    }
    int texcl = sdata[threadIdx.x] - tsum;
#pragma unroll
    for (int k = 0; k < SCAN_ITEMS; k++) {
        int idx = base + k;
        if (idx < n) off[idx] = texcl + vals[k];
    }
    if (threadIdx.x == THREADS - 1) bsums[blockIdx.x] = sdata[THREADS - 1];
}

__global__ void scan2_kernel(const int* __restrict__ bsums, int* __restrict__ bbase,
                             int nb, int* __restrict__ offN) {
    if (threadIdx.x == 0 && blockIdx.x == 0) {
        int run = 0;
        for (int i = 0; i < nb; i++) { bbase[i] = run; run += bsums[i]; }
        *offN = run;
    }
}

__global__ void scan3_kernel(int* __restrict__ off, int* __restrict__ pos,
                             const int* __restrict__ bbase, int n) {
    int i = blockIdx.x * blockDim.x + threadIdx.x;
    if (i < n) {
        int v = off[i] + bbase[i >> 11];
        off[i] = v;
        pos[i] = v;
    }
}

__global__ void bucket_kernel(const int* __restrict__ src, const int* __restrict__ dst,
                              int* __restrict__ pos, int* __restrict__ srcs, int E) {
    int e = blockIdx.x * blockDim.x + threadIdx.x;
    if (e < E) {
        int d = dst[e];
        int p = atomicAdd(&pos[d], 1);
        srcs[p] = src[e];
    }
}

// ---------------- precision prep ----------------
// fp32 -> bf16 bulk convert (float4 -> ushort4)
__global__ void cvt_bf16_kernel(const float4* __restrict__ x, ushort4* __restrict__ o, int n4) {
    int i = blockIdx.x * blockDim.x + threadIdx.x;
    if (i < n4) {
        float4 v = x[i];
        ushort4 r;
        r.x = f32_to_bf16_rne(v.x);
        r.y = f32_to_bf16_rne(v.y);
        r.z = f32_to_bf16_rne(v.z);
        r.w = f32_to_bf16_rne(v.w);
        o[i] = r;
    }
}

// Build swizzled hi/lo bf16 weight buffer for one layer.
// W256[k][n]: k<128 -> Wn[k][n], else Wr[k-128][n].
// Layout: [t(8 ktiles)][nt(8)][plane(hi=0,lo=1)][lane(64)][j(8) bf16] ; 16B per lane.
// Fragment mapping (16x16x32 bf16): B[k][n] with n = lane&15, k = t*32 + (lane>>4)*8 + j.
__global__ void swizzle_w_kernel(const float* __restrict__ Wn, const float* __restrict__ Wr,
                                 uint4* __restrict__ out) {
    int id = blockIdx.x * blockDim.x + threadIdx.x;  // 4096 = 8*8*64
    if (id >= 4096) return;
    int lane = id & 63;
    int nt = (id >> 6) & 7;
    int t = id >> 9;
    int kbase = t * 32 + (lane >> 4) * 8;
    int col = nt * 16 + (lane & 15);
    unsigned short hi[8], lo[8];
#pragma unroll
    for (int j = 0; j < 8; j++) {
        int k = kbase + j;
        const float* W = (k < 128) ? (Wn + (size_t)k * 128) : (Wr + (size_t)(k - 128) * 128);
        float v = W[col];
        unsigned short h = f32_to_bf16_rne(v);
        float hf = bf16_bits_to_f32(h);
        hi[j] = h;
        lo[j] = f32_to_bf16_rne(v - hf);
    }
    out[(size_t)((t * 8 + nt) * 2 + 0) * 64 + lane] = pack8(hi);
    out[(size_t)((t * 8 + nt) * 2 + 1) * 64 + lane] = pack8(lo);
}

// ---------------- aggregation (bf16 gather, fp32 accumulate) ----------------
// One wave per node; lane owns 2 features (one dword = 2 bf16). 4-edge unroll for MLP.
__global__ void agg_kernel(const unsigned short* __restrict__ hb, const int* __restrict__ off,
                           const int* __restrict__ srcs, const int* __restrict__ cnt,
                           float* __restrict__ agg, int n) {
    int gid = blockIdx.x * blockDim.x + threadIdx.x;
    int node = gid >> 6;
    int lane = threadIdx.x & 63;
    if (node >= n) return;
    int p0 = off[node], p1 = off[node + 1];
    float ax = 0.f, ay = 0.f;
    int p = p0;
    for (; p + 4 <= p1; p += 4) {
        int s0 = srcs[p], s1 = srcs[p + 1], s2 = srcs[p + 2], s3 = srcs[p + 3];
        unsigned int v0 = *(const unsigned int*)(hb + (size_t)s0 * 128 + lane * 2);
        unsigned int v1 = *(const unsigned int*)(hb + (size_t)s1 * 128 + lane * 2);
        unsigned int v2 = *(const unsigned int*)(hb + (size_t)s2 * 128 + lane * 2);
        unsigned int v3 = *(const unsigned int*)(hb + (size_t)s3 * 128 + lane * 2);
        ax += __uint_as_float(v0 << 16) + __uint_as_float(v1 << 16)
            + __uint_as_float(v2 << 16) + __uint_as_float(v3 << 16);
        ay += __uint_as_float(v0 & 0xffff0000u) + __uint_as_float(v1 & 0xffff0000u)
            + __uint_as_float(v2 & 0xffff0000u) + __uint_as_float(v3 & 0xffff0000u);
    }
    for (; p < p1; p++) {
        int s = srcs[p];
        unsigned int v = *(const unsigned int*)(hb + (size_t)s * 128 + lane * 2);
        ax += __uint_as_float(v << 16);
        ay += __uint_as_float(v & 0xffff0000u);
    }
    int c = cnt[node];
    float inv = 1.0f / (float)(c > 1 ? c : 1);
    *(float2*)(agg + (size_t)node * 128 + lane * 2) = make_float2(ax * inv, ay * inv);
}

// ---------------- fused SAGE update via split-bf16 MFMA ----------------
// C[N,128] = relu([agg | h] (N,256) @ [Wn;Wr] (256,128) + b); optionally head-fused.
// Block: 256 thr = 4 waves, 128 nodes. K chunked by 64 (4 chunks).
// A split: a = hi + lo (bf16 each); W pre-split. acc += Ah*Bh + Ah*Bl + Al*Bh.
// HSRC: 0 -> h is fp32 (x), 1 -> h is bf16 (h0b).
template <int HSRC, bool FINAL>
__global__ __launch_bounds__(256, 2) void update_mfma(
    const float* __restrict__ agg, const void* __restrict__ hsrc,
    const uint4* __restrict__ Wsw, const float* __restrict__ bias,
    unsigned short* __restrict__ hout,  // bf16 [n,128] if !FINAL
    const float* __restrict__ Wh, const float* __restrict__ bh,
    float* __restrict__ logits, int n) {
    __shared__ uint4 Alds[2048];  // [mt(8)][kt(2)][plane(2)][lane(64)] 16B -> 32 KB
    __shared__ uint4 Wlds[2048];  // [kt(2)][nt(8)][plane(2)][lane(64)] 16B -> 32 KB
    const int tid = threadIdx.x;
    const int lane = tid & 63;
    const int w = tid >> 6;
    const int i0 = blockIdx.x * 128;

    f32x4 acc[2][8];
#pragma unroll
    for (int mt = 0; mt < 2; mt++)
#pragma unroll
        for (int nt = 0; nt < 8; nt++) acc[mt][nt] = (f32x4)0.f;

    const int r = tid >> 1;          // node within tile, 0..127
    const int half = tid & 1;        // which 32-k half of the 64-k chunk
    const int rg = i0 + r;
    const bool inb = rg < n;
    const int mt_s = r >> 4;
    const int lidx = r & 15;

    for (int c = 0; c < 4; c++) {
        // ---- stage W chunk: 32 KB contiguous copy ----
        {
            const uint4* srcW = Wsw + (size_t)c * 2048;
#pragma unroll
            for (int g = 0; g < 8; g++) Wlds[g * 256 + tid] = srcW[g * 256 + tid];
        }
        // ---- stage A chunk: 128 nodes x 64 k, split hi/lo ----
        {
            unsigned short hiA[32], loA[32];
            if (c < 2) {
                const float4* src = (const float4*)(agg + (size_t)rg * 128 + c * 64 + half * 32);
#pragma unroll
                for (int q = 0; q < 8; q++) {
                    float4 f = inb ? src[q] : make_float4(0.f, 0.f, 0.f, 0.f);
                    float vv[4] = {f.x, f.y, f.z, f.w};
#pragma unroll
                    for (int e = 0; e < 4; e++) {
                        unsigned short h = f32_to_bf16_rne(vv[e]);
                        hiA[q * 4 + e] = h;
                        loA[q * 4 + e] = f32_to_bf16_rne(vv[e] - bf16_bits_to_f32(h));
                    }
                }
            } else if (HSRC == 0) {
                const float4* src = (const float4*)((const float*)hsrc + (size_t)rg * 128 +
                                                    (c - 2) * 64 + half * 32);
#pragma unroll
                for (int q = 0; q < 8; q++) {
                    float4 f = inb ? src[q] : make_float4(0.f, 0.f, 0.f, 0.f);
                    float vv[4] = {f.x, f.y, f.z, f.w};
#pragma unroll
                    for (int e = 0; e < 4; e++) {
                        unsigned short h = f32_to_bf16_rne(vv[e]);
                        hiA[q * 4 + e] = h;
                        loA[q * 4 + e] = f32_to_bf16_rne(vv[e] - bf16_bits_to_f32(h));
                    }
                }
            } else {
                const uint4* src = (const uint4*)((const unsigned short*)hsrc + (size_t)rg * 128 +
                                                  (c - 2) * 64 + half * 32);
#pragma unroll
                for (int q = 0; q < 4; q++) {
                    uint4 u = inb ? src[q] : make_uint4(0, 0, 0, 0);
                    unsigned int uu[4] = {u.x, u.y, u.z, u.w};
#pragma unroll
                    for (int e = 0; e < 4; e++) {
                        hiA[q * 8 + e * 2 + 0] = (unsigned short)(uu[e] & 0xffffu);
                        hiA[q * 8 + e * 2 + 1] = (unsigned short)(uu[e] >> 16);
                        loA[q * 8 + e * 2 + 0] = 0;
                        loA[q * 8 + e * 2 + 1] = 0;
                    }
                }
            }
            unsigned int baseHi = ((mt_s * 2 + half) * 2 + 0) * 64;
            unsigned int baseLo = baseHi + 64;
#pragma unroll
            for (int g2 = 0; g2 < 4; g2++) {
                Alds[baseHi + lidx + 16 * g2] = pack8(&hiA[g2 * 8]);
                Alds[baseLo + lidx + 16 * g2] = pack8(&loA[g2 * 8]);
            }
        }
        __syncthreads();
        // ---- compute ----
#pragma unroll
        for (int kt = 0; kt < 2; kt++) {
            bf16x8 a0h = *(const bf16x8*)&Alds[(((w * 2 + 0) * 2 + kt) * 2 + 0) * 64 + lane];
            bf16x8 a0l = *(const bf16x8*)&Alds[(((w * 2 + 0) * 2 + kt) * 2 + 1) * 64 + lane];
            bf16x8 a1h = *(const bf16x8*)&Alds[(((w * 2 + 1) * 2 + kt) * 2 + 0) * 64 + lane];
            bf16x8 a1l = *(const bf16x8*)&Alds[(((w * 2 + 1) * 2 + kt) * 2 + 1) * 64 + lane];
#pragma unroll
            for (int nt = 0; nt < 8; nt++) {
                bf16x8 bhv = *(const bf16x8*)&Wlds[((kt * 8 + nt) * 2 + 0) * 64 + lane];
                bf16x8 blv = *(const bf16x8*)&Wlds[((kt * 8 + nt) * 2 + 1) * 64 + lane];
                acc[0][nt] = __builtin_amdgcn_mfma_f32_16x16x32_bf16(a0h, bhv, acc[0][nt], 0, 0, 0);
                acc[0][nt] = __builtin_amdgcn_mfma_f32_16x16x32_bf16(a0h, blv, acc[0][nt], 0, 0, 0);
                acc[0][nt] = __builtin_amdgcn_mfma_f32_16x16x32_bf16(a0l, bhv, acc[0][nt], 0, 0, 0);
                acc[1][nt] = __builtin_amdgcn_mfma_f32_16x16x32_bf16(a1h, bhv, acc[1][nt], 0, 0, 0);
                acc[1][nt] = __builtin_amdgcn_mfma_f32_16x16x32_bf16(a1h, blv, acc[1][nt], 0, 0, 0);
                acc[1][nt] = __builtin_amdgcn_mfma_f32_16x16x32_bf16(a1l, bhv, acc[1][nt], 0, 0, 0);
            }
        }
        __syncthreads();
    }

    // ---- epilogue ----
    const int col = lane & 15;
    const int g4 = lane >> 4;
    float bcol[8];
#pragma unroll
    for (int nt = 0; nt < 8; nt++) bcol[nt] = bias[nt * 16 + col];
    if (!FINAL) {
#pragma unroll
        for (int mt = 0; mt < 2; mt++) {
            int nodeBase = i0 + (w * 2 + mt) * 16 + g4 * 4;
#pragma unroll
            for (int reg = 0; reg < 4; reg++) {
                int node = nodeBase + reg;
                if (node < n) {
#pragma unroll
                    for (int nt = 0; nt < 8; nt++) {
                        float v = acc[mt][nt][reg] + bcol[nt];
                        v = v > 0.f ? v : 0.f;
                        hout[(size_t)node * 128 + nt * 16 + col] = f32_to_bf16_rne(v);
                    }
                }
            }
        }
    } else {
        float whc[8];
#pragma unroll
        for (int nt = 0; nt < 8; nt++) whc[nt] = Wh[nt * 16 + col];
        float bhv = bh[0];
#pragma unroll
        for (int mt = 0; mt < 2; mt++) {
            int nodeBase = i0 + (w * 2 + mt) * 16 + g4 * 4;
#pragma unroll
            for (int reg = 0; reg < 4; reg++) {
                float s = 0.f;
#pragma unroll
                for (int nt = 0; nt < 8; nt++) {
                    float v = acc[mt][nt][reg] + bcol[nt];
                    v = v > 0.f ? v : 0.f;
                    s += v * whc[nt];
                }
                s += __shfl_xor(s, 1);
                s += __shfl_xor(s, 2);
                s += __shfl_xor(s, 4);
                s += __shfl_xor(s, 8);
                int node = nodeBase + reg;
                if (col == 0 && node < n) logits[node] = s + bhv;
            }
        }
    }
}

extern "C" void kernel_launch(void* const* d_in, const int* in_sizes, int n_in,
                              void* d_out, int out_size, void* d_ws, size_t ws_size,
                              hipStream_t stream) {
    const float* x   = (const float*)d_in[0];
    const int*   ei  = (const int*)d_in[1];
    const float* Wn0 = (const float*)d_in[2];
    const float* Wr0 = (const float*)d_in[3];
    const float* b0  = (const float*)d_in[4];
    const float* Wn1 = (const float*)d_in[5];
    const float* Wr1 = (const float*)d_in[6];
    const float* b1  = (const float*)d_in[7];
    const float* Wh  = (const float*)d_in[8];
    const float* bh  = (const float*)d_in[9];
    float* logits = (float*)d_out;

    int N = in_sizes[0] / 128;
    int E = in_sizes[1] / 2;
    const int* src = ei;
    const int* dst = ei + E;

    char* ws = (char*)d_ws;
    size_t cur = 0;
    auto alloc = [&](size_t bytes) -> void* {
        void* p = ws + cur;
        cur += (bytes + 255) & ~(size_t)255;
        return p;
    };
    int NB = (N + 2047) / 2048;
    int* cnt   = (int*)alloc((size_t)N * 4);
    int* off   = (int*)alloc((size_t)(N + 1) * 4);
    int* pos   = (int*)alloc((size_t)N * 4);
    int* bsums = (int*)alloc((size_t)NB * 4);
    int* bbase = (int*)alloc((size_t)NB * 4);
    int* srcs  = (int*)alloc((size_t)E * 4);
    unsigned short* xb  = (unsigned short*)alloc((size_t)N * 128 * 2);
    unsigned short* h0b = (unsigned short*)alloc((size_t)N * 128 * 2);
    float* ag  = (float*)alloc((size_t)N * 128 * 4);
    uint4* Wsw0 = (uint4*)alloc(131072);
    uint4* Wsw1 = (uint4*)alloc(131072);
    (void)ws_size; (void)n_in; (void)out_size;

    int gN = (N + 255) / 256;
    int gE = (E + 255) / 256;

    // CSR build
    hipLaunchKernelGGL(zero_int,      dim3(gN), dim3(256), 0, stream, cnt, N);
    hipLaunchKernelGGL(degree_kernel, dim3(gE), dim3(256), 0, stream, dst, cnt, E);
    hipLaunchKernelGGL(scan1_kernel,  dim3(NB), dim3(256), 0, stream, cnt, off, bsums, N);
    hipLaunchKernelGGL(scan2_kernel,  dim3(1),  dim3(64),  0, stream, bsums, bbase, NB, off + N);
    hipLaunchKernelGGL(scan3_kernel,  dim3(gN), dim3(256), 0, stream, off, pos, bbase, N);
    hipLaunchKernelGGL(bucket_kernel, dim3(gE), dim3(256), 0, stream, src, dst, pos, srcs, E);

    // Precision prep
    int n4 = N * 32;  // N*128/4
    hipLaunchKernelGGL(cvt_bf16_kernel, dim3((n4 + 255) / 256), dim3(256), 0, stream,
                       (const float4*)x, (ushort4*)xb, n4);
    hipLaunchKernelGGL(swizzle_w_kernel, dim3(16), dim3(256), 0, stream, Wn0, Wr0, Wsw0);
    hipLaunchKernelGGL(swizzle_w_kernel, dim3(16), dim3(256), 0, stream, Wn1, Wr1, Wsw1);

    int gAgg = (N + 3) / 4;      // 1 node per wave, 4 waves/block
    int gUpd = (N + 127) / 128;  // 128 nodes per block

    // Layer 0
    hipLaunchKernelGGL(agg_kernel, dim3(gAgg), dim3(256), 0, stream, xb, off, srcs, cnt, ag, N);
    hipLaunchKernelGGL((update_mfma<0, false>), dim3(gUpd), dim3(256), 0, stream,
                       ag, (const void*)x, Wsw0, b0, h0b, nullptr, nullptr, nullptr, N);
    // Layer 1 + fused head
    hipLaunchKernelGGL(agg_kernel, dim3(gAgg), dim3(256), 0, stream, h0b, off, srcs, cnt, ag, N);
    hipLaunchKernelGGL((update_mfma<1, true>), dim3(gUpd), dim3(256), 0, stream,
                       ag, (const void*)h0b, Wsw1, b1, nullptr, Wh, bh, logits, N);
}

// Round 3
// 459.431 us; speedup vs baseline: 1.8438x; 1.1979x over previous
//
#include <hip/hip_runtime.h>

#define THREADS 256
#define SCAN_ITEMS 8   // 2048 elements per scan block

typedef float f32x4 __attribute__((ext_vector_type(4)));
typedef __bf16 bf16x8 __attribute__((ext_vector_type(8)));

__device__ inline unsigned short f32_to_bf16_rne(float f) {
    unsigned int u = __float_as_uint(f);
    unsigned int r = u + 0x7fffu + ((u >> 16) & 1u);
    return (unsigned short)(r >> 16);
}
__device__ inline float bf16_bits_to_f32(unsigned short h) {
    return __uint_as_float(((unsigned int)h) << 16);
}
__device__ inline uint4 pack8(const unsigned short* s) {
    uint4 u;
    u.x = (unsigned int)s[0] | ((unsigned int)s[1] << 16);
    u.y = (unsigned int)s[2] | ((unsigned int)s[3] << 16);
    u.z = (unsigned int)s[4] | ((unsigned int)s[5] << 16);
    u.w = (unsigned int)s[6] | ((unsigned int)s[7] << 16);
    return u;
}

// ---------------- CSR build ----------------
__global__ void zero_int(int* __restrict__ p, int n) {
    int i = blockIdx.x * blockDim.x + threadIdx.x;
    if (i < n) p[i] = 0;
}

// Sliced histogram: block group g handles dst with (dst>>12)&7 == g.
// Atomics confined to a ~64 KB window per group -> L2-local.
__global__ void degree_sliced(const int* __restrict__ dst, int* __restrict__ cnt, int E) {
    const int g = blockIdx.x & 7;
    const int gb = blockIdx.x >> 3;
    const int nGb = gridDim.x >> 3;
    const int tid = threadIdx.x;
    const int e4 = E >> 2;
    const int4* dst4 = (const int4*)dst;
    for (int i = gb * blockDim.x + tid; i < e4; i += nGb * blockDim.x) {
        int4 d4 = dst4[i];
        int dd[4] = {d4.x, d4.y, d4.z, d4.w};
#pragma unroll
        for (int k = 0; k < 4; k++) {
            int d = dd[k];
            if (((d >> 12) & 7) == g) atomicAdd(&cnt[d], 1);
        }
    }
    if (gb == 0) {  // tail (E not multiple of 4)
        for (int e = (e4 << 2) + tid; e < E; e += blockDim.x) {
            int d = dst[e];
            if (((d >> 12) & 7) == g) atomicAdd(&cnt[d], 1);
        }
    }
}

__global__ void scan1_kernel(const int* __restrict__ cnt, int* __restrict__ off,
                             int* __restrict__ bsums, int n) {
    __shared__ int sdata[THREADS];
    int base = blockIdx.x * (THREADS * SCAN_ITEMS) + threadIdx.x * SCAN_ITEMS;
    int vals[SCAN_ITEMS];
    int tsum = 0;
#pragma unroll
    for (int k = 0; k < SCAN_ITEMS; k++) {
        int idx = base + k;
        int v = (idx < n) ? cnt[idx] : 0;
        vals[k] = tsum;
        tsum += v;
    }
    sdata[threadIdx.x] = tsum;
    __syncthreads();
    for (int s = 1; s < THREADS; s <<= 1) {
        int y = (threadIdx.x >= (unsigned)s) ? sdata[threadIdx.x - s] : 0;
        __syncthreads();
        sdata[threadIdx.x] += y;
        __syncthreads();
    }
    int texcl = sdata[threadIdx.x] - tsum;
#pragma unroll
    for (int k = 0; k < SCAN_ITEMS; k++) {
        int idx = base + k;
        if (idx < n) off[idx] = texcl + vals[k];
    }
    if (threadIdx.x == THREADS - 1) bsums[blockIdx.x] = sdata[THREADS - 1];
}

__global__ void scan2_kernel(const int* __restrict__ bsums, int* __restrict__ bbase,
                             int nb, int* __restrict__ offN) {
    if (threadIdx.x == 0 && blockIdx.x == 0) {
        int run = 0;
        for (int i = 0; i < nb; i++) { bbase[i] = run; run += bsums[i]; }
        *offN = run;
    }
}

__global__ void scan3_kernel(int* __restrict__ off, int* __restrict__ pos,
                             const int* __restrict__ bbase, int n) {
    int i = blockIdx.x * blockDim.x + threadIdx.x;
    if (i < n) {
        int v = off[i] + bbase[i >> 11];
        off[i] = v;
        pos[i] = v;
    }
}

// Sliced bucket fill: stores to srcs land in a ~800 KB window per group ->
// full-line dirty accumulation in L2 instead of 105 MB write-allocate churn.
__global__ void bucket_sliced(const int* __restrict__ src, const int* __restrict__ dst,
                              int* __restrict__ pos, int* __restrict__ srcs, int E) {
    const int g = blockIdx.x & 7;
    const int gb = blockIdx.x >> 3;
    const int nGb = gridDim.x >> 3;
    const int tid = threadIdx.x;
    const int e4 = E >> 2;
    const int4* dst4 = (const int4*)dst;
    for (int i = gb * blockDim.x + tid; i < e4; i += nGb * blockDim.x) {
        int4 d4 = dst4[i];
        int dd[4] = {d4.x, d4.y, d4.z, d4.w};
#pragma unroll
        for (int k = 0; k < 4; k++) {
            int d = dd[k];
            if (((d >> 12) & 7) == g) {
                int p = atomicAdd(&pos[d], 1);
                srcs[p] = src[i * 4 + k];
            }
        }
    }
    if (gb == 0) {
        for (int e = (e4 << 2) + tid; e < E; e += blockDim.x) {
            int d = dst[e];
            if (((d >> 12) & 7) == g) {
                int p = atomicAdd(&pos[d], 1);
                srcs[p] = src[e];
            }
        }
    }
}

// ---------------- precision prep ----------------
__global__ void cvt_bf16_kernel(const float4* __restrict__ x, ushort4* __restrict__ o, int n4) {
    int i = blockIdx.x * blockDim.x + threadIdx.x;
    if (i < n4) {
        float4 v = x[i];
        ushort4 r;
        r.x = f32_to_bf16_rne(v.x);
        r.y = f32_to_bf16_rne(v.y);
        r.z = f32_to_bf16_rne(v.z);
        r.w = f32_to_bf16_rne(v.w);
        o[i] = r;
    }
}

// Swizzled hi/lo bf16 weights. W256[k][n]: k<128 -> Wn, else Wr.
// [t(8)][nt(8)][plane(2)][lane(64)] x 16B; B frag: n = lane&15, k = t*32+(lane>>4)*8+j.
__global__ void swizzle_w_kernel(const float* __restrict__ Wn, const float* __restrict__ Wr,
                                 uint4* __restrict__ out) {
    int id = blockIdx.x * blockDim.x + threadIdx.x;
    if (id >= 4096) return;
    int lane = id & 63;
    int nt = (id >> 6) & 7;
    int t = id >> 9;
    int kbase = t * 32 + (lane >> 4) * 8;
    int col = nt * 16 + (lane & 15);
    unsigned short hi[8], lo[8];
#pragma unroll
    for (int j = 0; j < 8; j++) {
        int k = kbase + j;
        const float* W = (k < 128) ? (Wn + (size_t)k * 128) : (Wr + (size_t)(k - 128) * 128);
        float v = W[col];
        unsigned short h = f32_to_bf16_rne(v);
        hi[j] = h;
        lo[j] = f32_to_bf16_rne(v - bf16_bits_to_f32(h));
    }
    out[(size_t)((t * 8 + nt) * 2 + 0) * 64 + lane] = pack8(hi);
    out[(size_t)((t * 8 + nt) * 2 + 1) * 64 + lane] = pack8(lo);
}

// ---------------- aggregation (bf16 gather, fp32 acc, bf16 out) ----------------
__global__ void agg_kernel(const unsigned short* __restrict__ hb, const int* __restrict__ off,
                           const int* __restrict__ srcs, unsigned short* __restrict__ aggb,
                           int n) {
    int gid = blockIdx.x * blockDim.x + threadIdx.x;
    int node = gid >> 6;
    int lane = threadIdx.x & 63;
    if (node >= n) return;
    int p0 = off[node], p1 = off[node + 1];
    float ax = 0.f, ay = 0.f;
    int p = p0;
    for (; p + 4 <= p1; p += 4) {
        int s0 = srcs[p], s1 = srcs[p + 1], s2 = srcs[p + 2], s3 = srcs[p + 3];
        unsigned int v0 = *(const unsigned int*)(hb + (size_t)s0 * 128 + lane * 2);
        unsigned int v1 = *(const unsigned int*)(hb + (size_t)s1 * 128 + lane * 2);
        unsigned int v2 = *(const unsigned int*)(hb + (size_t)s2 * 128 + lane * 2);
        unsigned int v3 = *(const unsigned int*)(hb + (size_t)s3 * 128 + lane * 2);
        ax += __uint_as_float(v0 << 16) + __uint_as_float(v1 << 16)
            + __uint_as_float(v2 << 16) + __uint_as_float(v3 << 16);
        ay += __uint_as_float(v0 & 0xffff0000u) + __uint_as_float(v1 & 0xffff0000u)
            + __uint_as_float(v2 & 0xffff0000u) + __uint_as_float(v3 & 0xffff0000u);
    }
    for (; p < p1; p++) {
        int s = srcs[p];
        unsigned int v = *(const unsigned int*)(hb + (size_t)s * 128 + lane * 2);
        ax += __uint_as_float(v << 16);
        ay += __uint_as_float(v & 0xffff0000u);
    }
    int c = p1 - p0;
    float inv = 1.0f / (float)(c > 1 ? c : 1);
    unsigned int o = (unsigned int)f32_to_bf16_rne(ax * inv)
                   | ((unsigned int)f32_to_bf16_rne(ay * inv) << 16);
    *(unsigned int*)(aggb + (size_t)node * 128 + lane * 2) = o;
}

// ---------------- fused SAGE update via split-bf16 MFMA ----------------
// LAYER=0: hsrc is fp32 x (hi/lo split); LAYER=1: hsrc is bf16 h0b. agg is bf16.
template <int LAYER, bool FINAL>
__global__ __launch_bounds__(256, 2) void update_mfma(
    const unsigned short* __restrict__ aggb, const void* __restrict__ hsrc,
    const uint4* __restrict__ Wsw, const float* __restrict__ bias,
    unsigned short* __restrict__ hout,
    const float* __restrict__ Wh, const float* __restrict__ bh,
    float* __restrict__ logits, int n) {
    __shared__ uint4 Alds[2048];  // [mt(8)][kt(2)][plane(2)][lane(64)] 16B
    __shared__ uint4 Wlds[2048];  // [kt(2)][nt(8)][plane(2)][lane(64)] 16B
    const int tid = threadIdx.x;
    const int lane = tid & 63;
    const int w = tid >> 6;
    const int i0 = blockIdx.x * 128;

    f32x4 acc[2][8];
#pragma unroll
    for (int mt = 0; mt < 2; mt++)
#pragma unroll
        for (int nt = 0; nt < 8; nt++) acc[mt][nt] = (f32x4)0.f;

    const int r = tid >> 1;
    const int half = tid & 1;
    const int rg = i0 + r;
    const bool inb = rg < n;
    const int mt_s = r >> 4;
    const int lidx = r & 15;

    for (int c = 0; c < 4; c++) {
        const bool haslo = (LAYER == 0 && c >= 2);
        {
            const uint4* srcW = Wsw + (size_t)c * 2048;
#pragma unroll
            for (int g = 0; g < 8; g++) Wlds[g * 256 + tid] = srcW[g * 256 + tid];
        }
        {
            unsigned short hiA[32], loA[32];
            if (LAYER == 0 && c >= 2) {
                const float4* s4 = (const float4*)((const float*)hsrc + (size_t)rg * 128 +
                                                   (c - 2) * 64 + half * 32);
#pragma unroll
                for (int q = 0; q < 8; q++) {
                    float4 f = inb ? s4[q] : make_float4(0.f, 0.f, 0.f, 0.f);
                    float vv[4] = {f.x, f.y, f.z, f.w};
#pragma unroll
                    for (int e = 0; e < 4; e++) {
                        unsigned short h = f32_to_bf16_rne(vv[e]);
                        hiA[q * 4 + e] = h;
                        loA[q * 4 + e] = f32_to_bf16_rne(vv[e] - bf16_bits_to_f32(h));
                    }
                }
            } else {
                const unsigned short* bsrc = (c < 2) ? aggb : (const unsigned short*)hsrc;
                int cc = (c < 2) ? c : c - 2;
                const uint4* s4 = (const uint4*)(bsrc + (size_t)rg * 128 + cc * 64 + half * 32);
#pragma unroll
                for (int q = 0; q < 4; q++) {
                    uint4 u = inb ? s4[q] : make_uint4(0, 0, 0, 0);
                    unsigned int uu[4] = {u.x, u.y, u.z, u.w};
#pragma unroll
                    for (int e = 0; e < 4; e++) {
                        hiA[q * 8 + e * 2 + 0] = (unsigned short)(uu[e] & 0xffffu);
                        hiA[q * 8 + e * 2 + 1] = (unsigned short)(uu[e] >> 16);
                    }
                }
            }
            unsigned int baseHi = ((mt_s * 2 + half) * 2 + 0) * 64;
#pragma unroll
            for (int g2 = 0; g2 < 4; g2++)
                Alds[baseHi + lidx + 16 * g2] = pack8(&hiA[g2 * 8]);
            if (haslo) {
#pragma unroll
                for (int g2 = 0; g2 < 4; g2++)
                    Alds[baseHi + 64 + lidx + 16 * g2] = pack8(&loA[g2 * 8]);
            }
        }
        __syncthreads();
#pragma unroll
        for (int kt = 0; kt < 2; kt++) {
            bf16x8 a0h = *(const bf16x8*)&Alds[(((w * 2 + 0) * 2 + kt) * 2 + 0) * 64 + lane];
            bf16x8 a1h = *(const bf16x8*)&Alds[(((w * 2 + 1) * 2 + kt) * 2 + 0) * 64 + lane];
            bf16x8 a0l, a1l;
            if (haslo) {
                a0l = *(const bf16x8*)&Alds[(((w * 2 + 0) * 2 + kt) * 2 + 1) * 64 + lane];
                a1l = *(const bf16x8*)&Alds[(((w * 2 + 1) * 2 + kt) * 2 + 1) * 64 + lane];
            }
#pragma unroll
            for (int nt = 0; nt < 8; nt++) {
                bf16x8 bhv = *(const bf16x8*)&Wlds[((kt * 8 + nt) * 2 + 0) * 64 + lane];
                bf16x8 blv = *(const bf16x8*)&Wlds[((kt * 8 + nt) * 2 + 1) * 64 + lane];
                acc[0][nt] = __builtin_amdgcn_mfma_f32_16x16x32_bf16(a0h, bhv, acc[0][nt], 0, 0, 0);
                acc[0][nt] = __builtin_amdgcn_mfma_f32_16x16x32_bf16(a0h, blv, acc[0][nt], 0, 0, 0);
                acc[1][nt] = __builtin_amdgcn_mfma_f32_16x16x32_bf16(a1h, bhv, acc[1][nt], 0, 0, 0);
                acc[1][nt] = __builtin_amdgcn_mfma_f32_16x16x32_bf16(a1h, blv, acc[1][nt], 0, 0, 0);
                if (haslo) {
                    acc[0][nt] = __builtin_amdgcn_mfma_f32_16x16x32_bf16(a0l, bhv, acc[0][nt], 0, 0, 0);
                    acc[1][nt] = __builtin_amdgcn_mfma_f32_16x16x32_bf16(a1l, bhv, acc[1][nt], 0, 0, 0);
                }
            }
        }
        __syncthreads();
    }

    const int col = lane & 15;
    const int g4 = lane >> 4;
    float bcol[8];
#pragma unroll
    for (int nt = 0; nt < 8; nt++) bcol[nt] = bias[nt * 16 + col];
    if (!FINAL) {
#pragma unroll
        for (int mt = 0; mt < 2; mt++) {
            int nodeBase = i0 + (w * 2 + mt) * 16 + g4 * 4;
#pragma unroll
            for (int reg = 0; reg < 4; reg++) {
                int node = nodeBase + reg;
                if (node < n) {
#pragma unroll
                    for (int nt = 0; nt < 8; nt++) {
                        float v = acc[mt][nt][reg] + bcol[nt];
                        v = v > 0.f ? v : 0.f;
                        hout[(size_t)node * 128 + nt * 16 + col] = f32_to_bf16_rne(v);
                    }
                }
            }
        }
    } else {
        float whc[8];
#pragma unroll
        for (int nt = 0; nt < 8; nt++) whc[nt] = Wh[nt * 16 + col];
        float bhv = bh[0];
#pragma unroll
        for (int mt = 0; mt < 2; mt++) {
            int nodeBase = i0 + (w * 2 + mt) * 16 + g4 * 4;
#pragma unroll
            for (int reg = 0; reg < 4; reg++) {
                float s = 0.f;
#pragma unroll
                for (int nt = 0; nt < 8; nt++) {
                    float v = acc[mt][nt][reg] + bcol[nt];
                    v = v > 0.f ? v : 0.f;
                    s += v * whc[nt];
                }
                s += __shfl_xor(s, 1);
                s += __shfl_xor(s, 2);
                s += __shfl_xor(s, 4);
                s += __shfl_xor(s, 8);
                int node = nodeBase + reg;
                if (col == 0 && node < n) logits[node] = s + bhv;
            }
        }
    }
}

extern "C" void kernel_launch(void* const* d_in, const int* in_sizes, int n_in,
                              void* d_out, int out_size, void* d_ws, size_t ws_size,
                              hipStream_t stream) {
    const float* x   = (const float*)d_in[0];
    const int*   ei  = (const int*)d_in[1];
    const float* Wn0 = (const float*)d_in[2];
    const float* Wr0 = (const float*)d_in[3];
    const float* b0  = (const float*)d_in[4];
    const float* Wn1 = (const float*)d_in[5];
    const float* Wr1 = (const float*)d_in[6];
    const float* b1  = (const float*)d_in[7];
    const float* Wh  = (const float*)d_in[8];
    const float* bh  = (const float*)d_in[9];
    float* logits = (float*)d_out;

    int N = in_sizes[0] / 128;
    int E = in_sizes[1] / 2;
    const int* src = ei;
    const int* dst = ei + E;

    char* ws = (char*)d_ws;
    size_t cur = 0;
    auto alloc = [&](size_t bytes) -> void* {
        void* p = ws + cur;
        cur += (bytes + 255) & ~(size_t)255;
        return p;
    };
    int NB = (N + 2047) / 2048;
    int* cnt   = (int*)alloc((size_t)N * 4);
    int* off   = (int*)alloc((size_t)(N + 1) * 4);
    int* pos   = (int*)alloc((size_t)N * 4);
    int* bsums = (int*)alloc((size_t)NB * 4);
    int* bbase = (int*)alloc((size_t)NB * 4);
    int* srcs  = (int*)alloc((size_t)E * 4);
    unsigned short* xb  = (unsigned short*)alloc((size_t)N * 128 * 2);
    unsigned short* h0b = (unsigned short*)alloc((size_t)N * 128 * 2);
    unsigned short* agb = (unsigned short*)alloc((size_t)N * 128 * 2);
    uint4* Wsw0 = (uint4*)alloc(131072);
    uint4* Wsw1 = (uint4*)alloc(131072);
    (void)ws_size; (void)n_in; (void)out_size;

    int gN = (N + 255) / 256;

    // CSR build (sliced histogram + scatter)
    hipLaunchKernelGGL(zero_int,       dim3(gN),   dim3(256), 0, stream, cnt, N);
    hipLaunchKernelGGL(degree_sliced,  dim3(1024), dim3(256), 0, stream, dst, cnt, E);
    hipLaunchKernelGGL(scan1_kernel,   dim3(NB),   dim3(256), 0, stream, cnt, off, bsums, N);
    hipLaunchKernelGGL(scan2_kernel,   dim3(1),    dim3(64),  0, stream, bsums, bbase, NB, off + N);
    hipLaunchKernelGGL(scan3_kernel,   dim3(gN),   dim3(256), 0, stream, off, pos, bbase, N);
    hipLaunchKernelGGL(bucket_sliced,  dim3(1024), dim3(256), 0, stream, src, dst, pos, srcs, E);

    // Precision prep
    int n4 = N * 32;
    hipLaunchKernelGGL(cvt_bf16_kernel, dim3((n4 + 255) / 256), dim3(256), 0, stream,
                       (const float4*)x, (ushort4*)xb, n4);
    hipLaunchKernelGGL(swizzle_w_kernel, dim3(16), dim3(256), 0, stream, Wn0, Wr0, Wsw0);
    hipLaunchKernelGGL(swizzle_w_kernel, dim3(16), dim3(256), 0, stream, Wn1, Wr1, Wsw1);

    int gAgg = (N + 3) / 4;
    int gUpd = (N + 127) / 128;

    // Layer 0
    hipLaunchKernelGGL(agg_kernel, dim3(gAgg), dim3(256), 0, stream, xb, off, srcs, agb, N);
    hipLaunchKernelGGL((update_mfma<0, false>), dim3(gUpd), dim3(256), 0, stream,
                       agb, (const void*)x, Wsw0, b0, h0b, nullptr, nullptr, nullptr, N);
    // Layer 1 + fused head
    hipLaunchKernelGGL(agg_kernel, dim3(gAgg), dim3(256), 0, stream, h0b, off, srcs, agb, N);
    hipLaunchKernelGGL((update_mfma<1, true>), dim3(gUpd), dim3(256), 0, stream,
                       agb, (const void*)h0b, Wsw1, b1, nullptr, Wh, bh, logits, N);
}

// Round 4
// 444.461 us; speedup vs baseline: 1.9059x; 1.0337x over previous
//
#include <hip/hip_runtime.h>

#define THREADS 256
#define SCAN_ITEMS 8   // 2048 elements per scan block

typedef float f32x4 __attribute__((ext_vector_type(4)));
typedef __bf16 bf16x8 __attribute__((ext_vector_type(8)));
typedef int intx4 __attribute__((ext_vector_type(4)));

__device__ inline unsigned short f32_to_bf16_rne(float f) {
    unsigned int u = __float_as_uint(f);
    unsigned int r = u + 0x7fffu + ((u >> 16) & 1u);
    return (unsigned short)(r >> 16);
}
__device__ inline float bf16_bits_to_f32(unsigned short h) {
    return __uint_as_float(((unsigned int)h) << 16);
}
__device__ inline uint4 pack8(const unsigned short* s) {
    uint4 u;
    u.x = (unsigned int)s[0] | ((unsigned int)s[1] << 16);
    u.y = (unsigned int)s[2] | ((unsigned int)s[3] << 16);
    u.z = (unsigned int)s[4] | ((unsigned int)s[5] << 16);
    u.w = (unsigned int)s[6] | ((unsigned int)s[7] << 16);
    return u;
}

// ---------------- CSR build ----------------
__global__ void zero_int(int* __restrict__ p, int n) {
    int i = blockIdx.x * blockDim.x + threadIdx.x;
    if (i < n) p[i] = 0;
}

// Sliced histogram. nt loads: the 12.8 MB edge stream must NOT allocate in L2,
// so the ~50 KB of cnt atomic lines per XCD stay resident.
__global__ void degree_sliced(const int* __restrict__ dst, int* __restrict__ cnt, int E) {
    const int g = blockIdx.x & 7;
    const int gb = blockIdx.x >> 3;
    const int nGb = gridDim.x >> 3;
    const int tid = threadIdx.x;
    const int e4 = E >> 2;
    const intx4* dst4 = (const intx4*)dst;
    for (int i = gb * blockDim.x + tid; i < e4; i += nGb * blockDim.x) {
        intx4 d4 = __builtin_nontemporal_load(&dst4[i]);
#pragma unroll
        for (int k = 0; k < 4; k++) {
            int d = d4[k];
            if (((d >> 12) & 7) == g) atomicAdd(&cnt[d], 1);
        }
    }
    if (gb == 0) {
        for (int e = (e4 << 2) + tid; e < E; e += blockDim.x) {
            int d = dst[e];
            if (((d >> 12) & 7) == g) atomicAdd(&cnt[d], 1);
        }
    }
}

__global__ void scan1_kernel(const int* __restrict__ cnt, int* __restrict__ off,
                             int* __restrict__ bsums, int n) {
    __shared__ int sdata[THREADS];
    int base = blockIdx.x * (THREADS * SCAN_ITEMS) + threadIdx.x * SCAN_ITEMS;
    int vals[SCAN_ITEMS];
    int tsum = 0;
#pragma unroll
    for (int k = 0; k < SCAN_ITEMS; k++) {
        int idx = base + k;
        int v = (idx < n) ? cnt[idx] : 0;
        vals[k] = tsum;
        tsum += v;
    }
    sdata[threadIdx.x] = tsum;
    __syncthreads();
    for (int s = 1; s < THREADS; s <<= 1) {
        int y = (threadIdx.x >= (unsigned)s) ? sdata[threadIdx.x - s] : 0;
        __syncthreads();
        sdata[threadIdx.x] += y;
        __syncthreads();
    }
    int texcl = sdata[threadIdx.x] - tsum;
#pragma unroll
    for (int k = 0; k < SCAN_ITEMS; k++) {
        int idx = base + k;
        if (idx < n) off[idx] = texcl + vals[k];
    }
    if (threadIdx.x == THREADS - 1) bsums[blockIdx.x] = sdata[THREADS - 1];
}

__global__ void scan2_kernel(const int* __restrict__ bsums, int* __restrict__ bbase,
                             int nb, int* __restrict__ offN) {
    if (threadIdx.x == 0 && blockIdx.x == 0) {
        int run = 0;
        for (int i = 0; i < nb; i++) { bbase[i] = run; run += bsums[i]; }
        *offN = run;
    }
}

__global__ void scan3_kernel(int* __restrict__ off, int* __restrict__ pos,
                             const int* __restrict__ bbase, int n) {
    int i = blockIdx.x * blockDim.x + threadIdx.x;
    if (i < n) {
        int v = off[i] + bbase[i >> 11];
        off[i] = v;
        pos[i] = v;
    }
}

// Sliced bucket fill with nt streaming reads: keeps the ~850 KB dirty
// pos+srcs window per XCD resident in L2 so srcs lines fill before eviction.
__global__ void bucket_sliced(const int* __restrict__ src, const int* __restrict__ dst,
                              int* __restrict__ pos, int* __restrict__ srcs, int E) {
    const int g = blockIdx.x & 7;
    const int gb = blockIdx.x >> 3;
    const int nGb = gridDim.x >> 3;
    const int tid = threadIdx.x;
    const int e4 = E >> 2;
    const intx4* dst4 = (const intx4*)dst;
    for (int i = gb * blockDim.x + tid; i < e4; i += nGb * blockDim.x) {
        intx4 d4 = __builtin_nontemporal_load(&dst4[i]);
#pragma unroll
        for (int k = 0; k < 4; k++) {
            int d = d4[k];
            if (((d >> 12) & 7) == g) {
                int s = __builtin_nontemporal_load(&src[i * 4 + k]);
                int p = atomicAdd(&pos[d], 1);
                srcs[p] = s;
            }
        }
    }
    if (gb == 0) {
        for (int e = (e4 << 2) + tid; e < E; e += blockDim.x) {
            int d = dst[e];
            if (((d >> 12) & 7) == g) {
                int p = atomicAdd(&pos[d], 1);
                srcs[p] = src[e];
            }
        }
    }
}

// ---------------- precision prep ----------------
__global__ void cvt_bf16_kernel(const float4* __restrict__ x, ushort4* __restrict__ o, int n4) {
    int i = blockIdx.x * blockDim.x + threadIdx.x;
    if (i < n4) {
        float4 v = x[i];
        ushort4 r;
        r.x = f32_to_bf16_rne(v.x);
        r.y = f32_to_bf16_rne(v.y);
        r.z = f32_to_bf16_rne(v.z);
        r.w = f32_to_bf16_rne(v.w);
        o[i] = r;
    }
}

// Swizzled hi/lo bf16 weights. W256[k][n]: k<128 -> Wn, else Wr.
// [t(8)][nt(8)][plane(2)][lane(64)] x 16B; B frag: n = lane&15, k = t*32+(lane>>4)*8+j.
__global__ void swizzle_w_kernel(const float* __restrict__ Wn, const float* __restrict__ Wr,
                                 uint4* __restrict__ out) {
    int id = blockIdx.x * blockDim.x + threadIdx.x;
    if (id >= 4096) return;
    int lane = id & 63;
    int nt = (id >> 6) & 7;
    int t = id >> 9;
    int kbase = t * 32 + (lane >> 4) * 8;
    int col = nt * 16 + (lane & 15);
    unsigned short hi[8], lo[8];
#pragma unroll
    for (int j = 0; j < 8; j++) {
        int k = kbase + j;
        const float* W = (k < 128) ? (Wn + (size_t)k * 128) : (Wr + (size_t)(k - 128) * 128);
        float v = W[col];
        unsigned short h = f32_to_bf16_rne(v);
        hi[j] = h;
        lo[j] = f32_to_bf16_rne(v - bf16_bits_to_f32(h));
    }
    out[(size_t)((t * 8 + nt) * 2 + 0) * 64 + lane] = pack8(hi);
    out[(size_t)((t * 8 + nt) * 2 + 1) * 64 + lane] = pack8(lo);
}

// ---------------- aggregation (bf16 gather, fp32 acc, bf16 out) ----------------
// One wave per node. Lane-distributed srcs prefetch (1 vector load replaces up
// to 64 serial scalar loads) + 8-wide gather unroll => 8 row loads in flight.
__global__ void agg_kernel(const unsigned short* __restrict__ hb, const int* __restrict__ off,
                           const int* __restrict__ srcs, unsigned short* __restrict__ aggb,
                           int n) {
    int gid = blockIdx.x * blockDim.x + threadIdx.x;
    int node = gid >> 6;
    int lane = threadIdx.x & 63;
    if (node >= n) return;
    int p0 = off[node], p1 = off[node + 1];
    int deg = p1 - p0;
    float ax = 0.f, ay = 0.f;
    for (int base = 0; base < deg; base += 64) {
        int m = deg - base; if (m > 64) m = 64;
        int sidx = (lane < m) ? __builtin_nontemporal_load(&srcs[p0 + base + lane]) : 0;
        int e = 0;
        for (; e + 8 <= m; e += 8) {
            unsigned int v[8];
#pragma unroll
            for (int u = 0; u < 8; u++) {
                int s = __shfl(sidx, e + u);
                v[u] = *(const unsigned int*)(hb + (size_t)s * 128 + lane * 2);
            }
#pragma unroll
            for (int u = 0; u < 8; u++) {
                ax += __uint_as_float(v[u] << 16);
                ay += __uint_as_float(v[u] & 0xffff0000u);
            }
        }
        for (; e < m; e++) {
            int s = __shfl(sidx, e);
            unsigned int v = *(const unsigned int*)(hb + (size_t)s * 128 + lane * 2);
            ax += __uint_as_float(v << 16);
            ay += __uint_as_float(v & 0xffff0000u);
        }
    }
    float inv = 1.0f / (float)(deg > 1 ? deg : 1);
    unsigned int o = (unsigned int)f32_to_bf16_rne(ax * inv)
                   | ((unsigned int)f32_to_bf16_rne(ay * inv) << 16);
    *(unsigned int*)(aggb + (size_t)node * 128 + lane * 2) = o;
}

// ---------------- fused SAGE update via split-bf16 MFMA ----------------
// LAYER=0: hsrc is fp32 x (hi/lo split); LAYER=1: hsrc is bf16 h0b. agg is bf16.
template <int LAYER, bool FINAL>
__global__ __launch_bounds__(256, 2) void update_mfma(
    const unsigned short* __restrict__ aggb, const void* __restrict__ hsrc,
    const uint4* __restrict__ Wsw, const float* __restrict__ bias,
    unsigned short* __restrict__ hout,
    const float* __restrict__ Wh, const float* __restrict__ bh,
    float* __restrict__ logits, int n) {
    __shared__ uint4 Alds[2048];  // [mt(8)][kt(2)][plane(2)][lane(64)] 16B
    __shared__ uint4 Wlds[2048];  // [kt(2)][nt(8)][plane(2)][lane(64)] 16B
    const int tid = threadIdx.x;
    const int lane = tid & 63;
    const int w = tid >> 6;
    const int i0 = blockIdx.x * 128;

    f32x4 acc[2][8];
#pragma unroll
    for (int mt = 0; mt < 2; mt++)
#pragma unroll
        for (int nt = 0; nt < 8; nt++) acc[mt][nt] = (f32x4)0.f;

    const int r = tid >> 1;
    const int half = tid & 1;
    const int rg = i0 + r;
    const bool inb = rg < n;
    const int mt_s = r >> 4;
    const int lidx = r & 15;

    for (int c = 0; c < 4; c++) {
        const bool haslo = (LAYER == 0 && c >= 2);
        {
            const uint4* srcW = Wsw + (size_t)c * 2048;
#pragma unroll
            for (int g = 0; g < 8; g++) Wlds[g * 256 + tid] = srcW[g * 256 + tid];
        }
        {
            unsigned short hiA[32], loA[32];
            if (LAYER == 0 && c >= 2) {
                const float4* s4 = (const float4*)((const float*)hsrc + (size_t)rg * 128 +
                                                   (c - 2) * 64 + half * 32);
#pragma unroll
                for (int q = 0; q < 8; q++) {
                    float4 f = inb ? s4[q] : make_float4(0.f, 0.f, 0.f, 0.f);
                    float vv[4] = {f.x, f.y, f.z, f.w};
#pragma unroll
                    for (int e = 0; e < 4; e++) {
                        unsigned short h = f32_to_bf16_rne(vv[e]);
                        hiA[q * 4 + e] = h;
                        loA[q * 4 + e] = f32_to_bf16_rne(vv[e] - bf16_bits_to_f32(h));
                    }
                }
            } else {
                const unsigned short* bsrc = (c < 2) ? aggb : (const unsigned short*)hsrc;
                int cc = (c < 2) ? c : c - 2;
                const uint4* s4 = (const uint4*)(bsrc + (size_t)rg * 128 + cc * 64 + half * 32);
#pragma unroll
                for (int q = 0; q < 4; q++) {
                    uint4 u = inb ? s4[q] : make_uint4(0, 0, 0, 0);
                    unsigned int uu[4] = {u.x, u.y, u.z, u.w};
#pragma unroll
                    for (int e = 0; e < 4; e++) {
                        hiA[q * 8 + e * 2 + 0] = (unsigned short)(uu[e] & 0xffffu);
                        hiA[q * 8 + e * 2 + 1] = (unsigned short)(uu[e] >> 16);
                    }
                }
            }
            unsigned int baseHi = ((mt_s * 2 + half) * 2 + 0) * 64;
#pragma unroll
            for (int g2 = 0; g2 < 4; g2++)
                Alds[baseHi + lidx + 16 * g2] = pack8(&hiA[g2 * 8]);
            if (haslo) {
#pragma unroll
                for (int g2 = 0; g2 < 4; g2++)
                    Alds[baseHi + 64 + lidx + 16 * g2] = pack8(&loA[g2 * 8]);
            }
        }
        __syncthreads();
#pragma unroll
        for (int kt = 0; kt < 2; kt++) {
            bf16x8 a0h = *(const bf16x8*)&Alds[(((w * 2 + 0) * 2 + kt) * 2 + 0) * 64 + lane];
            bf16x8 a1h = *(const bf16x8*)&Alds[(((w * 2 + 1) * 2 + kt) * 2 + 0) * 64 + lane];
            bf16x8 a0l, a1l;
            if (haslo) {
                a0l = *(const bf16x8*)&Alds[(((w * 2 + 0) * 2 + kt) * 2 + 1) * 64 + lane];
                a1l = *(const bf16x8*)&Alds[(((w * 2 + 1) * 2 + kt) * 2 + 1) * 64 + lane];
            }
#pragma unroll
            for (int nt = 0; nt < 8; nt++) {
                bf16x8 bhv = *(const bf16x8*)&Wlds[((kt * 8 + nt) * 2 + 0) * 64 + lane];
                bf16x8 blv = *(const bf16x8*)&Wlds[((kt * 8 + nt) * 2 + 1) * 64 + lane];
                acc[0][nt] = __builtin_amdgcn_mfma_f32_16x16x32_bf16(a0h, bhv, acc[0][nt], 0, 0, 0);
                acc[0][nt] = __builtin_amdgcn_mfma_f32_16x16x32_bf16(a0h, blv, acc[0][nt], 0, 0, 0);
                acc[1][nt] = __builtin_amdgcn_mfma_f32_16x16x32_bf16(a1h, bhv, acc[1][nt], 0, 0, 0);
                acc[1][nt] = __builtin_amdgcn_mfma_f32_16x16x32_bf16(a1h, blv, acc[1][nt], 0, 0, 0);
                if (haslo) {
                    acc[0][nt] = __builtin_amdgcn_mfma_f32_16x16x32_bf16(a0l, bhv, acc[0][nt], 0, 0, 0);
                    acc[1][nt] = __builtin_amdgcn_mfma_f32_16x16x32_bf16(a1l, bhv, acc[1][nt], 0, 0, 0);
                }
            }
        }
        __syncthreads();
    }

    const int col = lane & 15;
    const int g4 = lane >> 4;
    float bcol[8];
#pragma unroll
    for (int nt = 0; nt < 8; nt++) bcol[nt] = bias[nt * 16 + col];
    if (!FINAL) {
#pragma unroll
        for (int mt = 0; mt < 2; mt++) {
            int nodeBase = i0 + (w * 2 + mt) * 16 + g4 * 4;
#pragma unroll
            for (int reg = 0; reg < 4; reg++) {
                int node = nodeBase + reg;
                if (node < n) {
#pragma unroll
                    for (int nt = 0; nt < 8; nt++) {
                        float v = acc[mt][nt][reg] + bcol[nt];
                        v = v > 0.f ? v : 0.f;
                        hout[(size_t)node * 128 + nt * 16 + col] = f32_to_bf16_rne(v);
                    }
                }
            }
        }
    } else {
        float whc[8];
#pragma unroll
        for (int nt = 0; nt < 8; nt++) whc[nt] = Wh[nt * 16 + col];
        float bhv = bh[0];
#pragma unroll
        for (int mt = 0; mt < 2; mt++) {
            int nodeBase = i0 + (w * 2 + mt) * 16 + g4 * 4;
#pragma unroll
            for (int reg = 0; reg < 4; reg++) {
                float s = 0.f;
#pragma unroll
                for (int nt = 0; nt < 8; nt++) {
                    float v = acc[mt][nt][reg] + bcol[nt];
                    v = v > 0.f ? v : 0.f;
                    s += v * whc[nt];
                }
                s += __shfl_xor(s, 1);
                s += __shfl_xor(s, 2);
                s += __shfl_xor(s, 4);
                s += __shfl_xor(s, 8);
                int node = nodeBase + reg;
                if (col == 0 && node < n) logits[node] = s + bhv;
            }
        }
    }
}

extern "C" void kernel_launch(void* const* d_in, const int* in_sizes, int n_in,
                              void* d_out, int out_size, void* d_ws, size_t ws_size,
                              hipStream_t stream) {
    const float* x   = (const float*)d_in[0];
    const int*   ei  = (const int*)d_in[1];
    const float* Wn0 = (const float*)d_in[2];
    const float* Wr0 = (const float*)d_in[3];
    const float* b0  = (const float*)d_in[4];
    const float* Wn1 = (const float*)d_in[5];
    const float* Wr1 = (const float*)d_in[6];
    const float* b1  = (const float*)d_in[7];
    const float* Wh  = (const float*)d_in[8];
    const float* bh  = (const float*)d_in[9];
    float* logits = (float*)d_out;

    int N = in_sizes[0] / 128;
    int E = in_sizes[1] / 2;
    const int* src = ei;
    const int* dst = ei + E;

    char* ws = (char*)d_ws;
    size_t cur = 0;
    auto alloc = [&](size_t bytes) -> void* {
        void* p = ws + cur;
        cur += (bytes + 255) & ~(size_t)255;
        return p;
    };
    int NB = (N + 2047) / 2048;
    int* cnt   = (int*)alloc((size_t)N * 4);
    int* off   = (int*)alloc((size_t)(N + 1) * 4);
    int* pos   = (int*)alloc((size_t)N * 4);
    int* bsums = (int*)alloc((size_t)NB * 4);
    int* bbase = (int*)alloc((size_t)NB * 4);
    int* srcs  = (int*)alloc((size_t)E * 4);
    unsigned short* xb  = (unsigned short*)alloc((size_t)N * 128 * 2);
    unsigned short* h0b = (unsigned short*)alloc((size_t)N * 128 * 2);
    unsigned short* agb = (unsigned short*)alloc((size_t)N * 128 * 2);
    uint4* Wsw0 = (uint4*)alloc(131072);
    uint4* Wsw1 = (uint4*)alloc(131072);
    (void)ws_size; (void)n_in; (void)out_size;

    int gN = (N + 255) / 256;

    // CSR build (sliced histogram + scatter, nt streaming reads)
    hipLaunchKernelGGL(zero_int,       dim3(gN),   dim3(256), 0, stream, cnt, N);
    hipLaunchKernelGGL(degree_sliced,  dim3(1024), dim3(256), 0, stream, dst, cnt, E);
    hipLaunchKernelGGL(scan1_kernel,   dim3(NB),   dim3(256), 0, stream, cnt, off, bsums, N);
    hipLaunchKernelGGL(scan2_kernel,   dim3(1),    dim3(64),  0, stream, bsums, bbase, NB, off + N);
    hipLaunchKernelGGL(scan3_kernel,   dim3(gN),   dim3(256), 0, stream, off, pos, bbase, N);
    hipLaunchKernelGGL(bucket_sliced,  dim3(1024), dim3(256), 0, stream, src, dst, pos, srcs, E);

    // Precision prep
    int n4 = N * 32;
    hipLaunchKernelGGL(cvt_bf16_kernel, dim3((n4 + 255) / 256), dim3(256), 0, stream,
                       (const float4*)x, (ushort4*)xb, n4);
    hipLaunchKernelGGL(swizzle_w_kernel, dim3(16), dim3(256), 0, stream, Wn0, Wr0, Wsw0);
    hipLaunchKernelGGL(swizzle_w_kernel, dim3(16), dim3(256), 0, stream, Wn1, Wr1, Wsw1);

    int gAgg = (N + 3) / 4;
    int gUpd = (N + 127) / 128;

    // Layer 0
    hipLaunchKernelGGL(agg_kernel, dim3(gAgg), dim3(256), 0, stream, xb, off, srcs, agb, N);
    hipLaunchKernelGGL((update_mfma<0, false>), dim3(gUpd), dim3(256), 0, stream,
                       agb, (const void*)x, Wsw0, b0, h0b, nullptr, nullptr, nullptr, N);
    // Layer 1 + fused head
    hipLaunchKernelGGL(agg_kernel, dim3(gAgg), dim3(256), 0, stream, h0b, off, srcs, agb, N);
    hipLaunchKernelGGL((update_mfma<1, true>), dim3(gUpd), dim3(256), 0, stream,
                       agb, (const void*)h0b, Wsw1, b1, nullptr, Wh, bh, logits, N);
}